// Round 3
// baseline (655.820 us; speedup 1.0000x reference)
//
#include <hip/hip_runtime.h>
#include <hip/hip_bf16.h>

#define S_LEN 2048
#define DH    64
#define QT    64
#define KT    64
#define NW    4

typedef __attribute__((ext_vector_type(8))) short bf16x8;
typedef __attribute__((ext_vector_type(4))) float f32x4;

// round-to-nearest-even fp32 -> bf16 (inputs finite)
static __device__ __forceinline__ short f2b(float f) {
    unsigned u = __builtin_bit_cast(unsigned, f);
    unsigned r = (u + 0x7FFFu + ((u >> 16) & 1u)) >> 16;
    return (short)r;
}

__global__ __launch_bounds__(256) void attn_main(
    const float* __restrict__ Q, const float* __restrict__ K,
    const float* __restrict__ V, const int* __restrict__ PAD,
    float* __restrict__ OUT, float* __restrict__ W)
{
    __shared__ short Kt[KT][72];             // 9216 B, rows 144B
    __shared__ short VT[DH][72];             // 9216 B  (pass A only)
    __shared__ short Pb[NW][16][72];         // 9216 B  (pass A only, per-wave)
    __shared__ float sinv[NW][16];           // row 1/sum broadcast for pass B
    __shared__ unsigned long long padm[32];  // pad bitmask, 64 keys/word

    // XCD-aware swizzle: each XCD owns 256 consecutive logical wgs = 8 heads
    const int orig = blockIdx.x;
    const int wg   = (orig & 7) * 256 + (orig >> 3);
    const int bh   = wg >> 5;
    const int qt   = 31 - (wg & 31);        // heavy tiles first
    const int b    = bh >> 4;
    const int q0   = qt * QT;

    const int tid = threadIdx.x;
    const int wv  = tid >> 6;
    const int l   = tid & 63;
    const int lr  = l & 15;
    const int lg  = l >> 4;

    const size_t hoff = (size_t)bh * S_LEN * DH;
    const float* Qh = Q + hoff;
    const float* Kh = K + hoff;
    const float* Vh = V + hoff;
    float* Oh = OUT + hoff;
    float* Wh = W + (size_t)bh * S_LEN * S_LEN;

    const int nkt = qt + 1;

    // ---- prefetch tile kt=0 (K+V) into registers ----
    f32x4 pk0, pk1, pk2, pk3, pv0, pv1, pv2, pv3;
    {
        const float* kp = Kh + (size_t)l * DH + wv * 16;
        const float* vp = Vh + (size_t)l * DH + wv * 16;
        pk0 = *reinterpret_cast<const f32x4*>(kp);
        pk1 = *reinterpret_cast<const f32x4*>(kp + 4);
        pk2 = *reinterpret_cast<const f32x4*>(kp + 8);
        pk3 = *reinterpret_cast<const f32x4*>(kp + 12);
        pv0 = *reinterpret_cast<const f32x4*>(vp);
        pv1 = *reinterpret_cast<const f32x4*>(vp + 4);
        pv2 = *reinterpret_cast<const f32x4*>(vp + 8);
        pv3 = *reinterpret_cast<const f32x4*>(vp + 12);
    }

    // pad bitmask via wave ballot (first loop barrier publishes it)
    for (int i = tid; i < S_LEN; i += 256) {
        unsigned long long m = __ballot(PAD[b * S_LEN + i] != 0);
        if (l == 0) padm[i >> 6] = m;
    }

    // ---- Q fragments (16 rows/wave), scale 1/8 folded in ----
    const int qrow = q0 + wv * 16 + lr;
    bf16x8 qf[2];
    {
        const float* qp = Qh + (size_t)qrow * DH + lg * 8;
        #pragma unroll
        for (int h = 0; h < 2; ++h) {
            f32x4 a  = *reinterpret_cast<const f32x4*>(qp + h * 32);
            f32x4 b4 = *reinterpret_cast<const f32x4*>(qp + h * 32 + 4);
            #pragma unroll
            for (int j = 0; j < 4; ++j) {
                qf[h][j]     = f2b(a[j]  * 0.125f);
                qf[h][4 + j] = f2b(b4[j] * 0.125f);
            }
        }
    }

    const f32x4 z4 = {0.f, 0.f, 0.f, 0.f};
    f32x4 acc[4] = {z4, z4, z4, z4};
    float rs[4] = {0.f, 0.f, 0.f, 0.f};
    const int qa = q0 + wv * 16 + lg * 4;   // accumulator base row (add r)

    // =================== PASS A: rowsums + PV ===================
    for (int kt = 0; kt < nkt; ++kt) {
        __syncthreads();   // prev readers done; drains prefetch vmcnt (data needed now)
        {
            bf16x8 ta, tb;
            #pragma unroll
            for (int j = 0; j < 4; ++j) {
                ta[j] = f2b(pk0[j]); ta[4 + j] = f2b(pk1[j]);
                tb[j] = f2b(pk2[j]); tb[4 + j] = f2b(pk3[j]);
            }
            *reinterpret_cast<bf16x8*>(&Kt[l][wv * 16])     = ta;
            *reinterpret_cast<bf16x8*>(&Kt[l][wv * 16 + 8]) = tb;
            #pragma unroll
            for (int j = 0; j < 4; ++j) {
                VT[wv * 16 + j][l]      = f2b(pv0[j]);
                VT[wv * 16 + 4 + j][l]  = f2b(pv1[j]);
                VT[wv * 16 + 8 + j][l]  = f2b(pv2[j]);
                VT[wv * 16 + 12 + j][l] = f2b(pv3[j]);
            }
        }
        __syncthreads();   // tile kt visible

        // issue next tile's loads NOW -> in flight across the whole compute phase
        if (kt + 1 < nkt) {
            const float* kp = Kh + ((size_t)((kt + 1) * KT) + l) * DH + wv * 16;
            const float* vp = Vh + ((size_t)((kt + 1) * KT) + l) * DH + wv * 16;
            pk0 = *reinterpret_cast<const f32x4*>(kp);
            pk1 = *reinterpret_cast<const f32x4*>(kp + 4);
            pk2 = *reinterpret_cast<const f32x4*>(kp + 8);
            pk3 = *reinterpret_cast<const f32x4*>(kp + 12);
            pv0 = *reinterpret_cast<const f32x4*>(vp);
            pv1 = *reinterpret_cast<const f32x4*>(vp + 4);
            pv2 = *reinterpret_cast<const f32x4*>(vp + 8);
            pv3 = *reinterpret_cast<const f32x4*>(vp + 12);
        }

        const unsigned long long pm = padm[kt];

        // QK^T: 4 key-subtiles x 2 d-halves
        f32x4 sc[4] = {z4, z4, z4, z4};
        #pragma unroll
        for (int s = 0; s < 4; ++s)
            #pragma unroll
            for (int h = 0; h < 2; ++h) {
                bf16x8 kf = *reinterpret_cast<const bf16x8*>(&Kt[s * 16 + lr][h * 32 + lg * 8]);
                sc[s] = __builtin_amdgcn_mfma_f32_16x16x32_bf16(qf[h], kf, sc[s], 0, 0, 0);
            }

        // exp + masks + rowsum + P -> LDS (bf16)
        #pragma unroll
        for (int s = 0; s < 4; ++s) {
            const int kabs = kt * KT + s * 16 + lr;
            const bool padded = (pm >> (s * 16 + lr)) & 1ull;
            #pragma unroll
            for (int r = 0; r < 4; ++r) {
                const bool ok = (kabs <= qa + r) && !padded;
                const float e = ok ? __expf(sc[s][r]) : 0.f;
                rs[r] += e;
                Pb[wv][lg * 4 + r][s * 16 + lr] = f2b(e);
            }
        }
        // no barrier: Pb is per-wave

        // PV: acc[16q x 64d] += P(16x64) * V(64x64)
        #pragma unroll
        for (int kk = 0; kk < 2; ++kk) {
            bf16x8 pf = *reinterpret_cast<const bf16x8*>(&Pb[wv][lr][kk * 32 + lg * 8]);
            #pragma unroll
            for (int dt = 0; dt < 4; ++dt) {
                bf16x8 vf = *reinterpret_cast<const bf16x8*>(&VT[dt * 16 + lr][kk * 32 + lg * 8]);
                acc[dt] = __builtin_amdgcn_mfma_f32_16x16x32_bf16(pf, vf, acc[dt], 0, 0, 0);
            }
        }
    }

    // rowsum reduce across the 16 k-lanes
    #pragma unroll
    for (int r = 0; r < 4; ++r) {
        float v = rs[r];
        v += __shfl_xor(v, 1, 16);
        v += __shfl_xor(v, 2, 16);
        v += __shfl_xor(v, 4, 16);
        v += __shfl_xor(v, 8, 16);
        rs[r] = v;
    }
    float inv[4];
    #pragma unroll
    for (int r = 0; r < 4; ++r) inv[r] = rs[r] > 0.f ? 1.f / rs[r] : 0.f;  // 0 => fixup

    // broadcast inv to pass B layout (same-wave LDS, no barrier needed)
    if (lr == 0) {
        #pragma unroll
        for (int r = 0; r < 4; ++r) sinv[wv][lg * 4 + r] = inv[r];
    }

    // store attention output
    #pragma unroll
    for (int dt = 0; dt < 4; ++dt)
        #pragma unroll
        for (int r = 0; r < 4; ++r)
            Oh[(size_t)(qa + r) * DH + dt * 16 + lr] = acc[dt][r] * inv[r];

    // =================== PASS B: swapped QK^T, direct W stores ===================
    const float rinv = sinv[wv][lr];          // 1/rowsum for q row q0+wv*16+lr
    const int   qcol = q0 + wv * 16 + lr;

    // prefetch K tile kt=0
    {
        const float* kp = Kh + (size_t)l * DH + wv * 16;
        pk0 = *reinterpret_cast<const f32x4*>(kp);
        pk1 = *reinterpret_cast<const f32x4*>(kp + 4);
        pk2 = *reinterpret_cast<const f32x4*>(kp + 8);
        pk3 = *reinterpret_cast<const f32x4*>(kp + 12);
    }

    for (int kt = 0; kt < nkt; ++kt) {
        __syncthreads();   // protects Kt (also vs pass A's last readers)
        {
            bf16x8 ta, tb;
            #pragma unroll
            for (int j = 0; j < 4; ++j) {
                ta[j] = f2b(pk0[j]); ta[4 + j] = f2b(pk1[j]);
                tb[j] = f2b(pk2[j]); tb[4 + j] = f2b(pk3[j]);
            }
            *reinterpret_cast<bf16x8*>(&Kt[l][wv * 16])     = ta;
            *reinterpret_cast<bf16x8*>(&Kt[l][wv * 16 + 8]) = tb;
        }
        __syncthreads();

        if (kt + 1 < nkt) {
            const float* kp = Kh + ((size_t)((kt + 1) * KT) + l) * DH + wv * 16;
            pk0 = *reinterpret_cast<const f32x4*>(kp);
            pk1 = *reinterpret_cast<const f32x4*>(kp + 4);
            pk2 = *reinterpret_cast<const f32x4*>(kp + 8);
            pk3 = *reinterpret_cast<const f32x4*>(kp + 12);
        }

        const unsigned long long pm = padm[kt];

        // swapped: sc[s] = K_tile * Q^T -> D[row=key][col=q]
        f32x4 sc[4] = {z4, z4, z4, z4};
        #pragma unroll
        for (int s = 0; s < 4; ++s)
            #pragma unroll
            for (int h = 0; h < 2; ++h) {
                bf16x8 kf = *reinterpret_cast<const bf16x8*>(&Kt[s * 16 + lr][h * 32 + lg * 8]);
                sc[s] = __builtin_amdgcn_mfma_f32_16x16x32_bf16(kf, qf[h], sc[s], 0, 0, 0);
            }

        // lane holds keys kt*64 + s*16 + lg*4 + (0..3) for q row qcol -> direct f32x4 store
        #pragma unroll
        for (int s = 0; s < 4; ++s) {
            const int kbase = kt * KT + s * 16 + lg * 4;
            f32x4 t;
            #pragma unroll
            for (int r = 0; r < 4; ++r) {
                const bool padded = (pm >> (s * 16 + lg * 4 + r)) & 1ull;
                const bool ok = (kbase + r <= qcol) && !padded;
                t[r] = ok ? __expf(sc[s][r]) * rinv : 0.f;
            }
            *reinterpret_cast<f32x4*>(Wh + (size_t)qcol * S_LEN + kbase) = t;
        }
    }

    // zero-fill the beyond-causal rectangle k in [kend, S)
    {
        const int kend = q0 + QT;
        const int ntail4 = (S_LEN - kend) >> 2;
        for (int row = 0; row < QT; ++row) {
            f32x4* dst = reinterpret_cast<f32x4*>(Wh + (size_t)(q0 + row) * S_LEN + kend);
            for (int i = tid; i < ntail4; i += 256) dst[i] = z4;
        }
    }
}

// rows fully masked (all k<=q padded): reference softmax = uniform 1/S over ALL keys
__global__ __launch_bounds__(256) void attn_fixup(
    const int* __restrict__ PAD, const float* __restrict__ V,
    float* __restrict__ OUT, float* __restrict__ W)
{
    const int bh = blockIdx.x;
    const int b  = bh >> 4;
    const int tid = threadIdx.x;
    __shared__ int red;
    __shared__ float tmp[256];
    __shared__ float vs[DH];
    if (tid == 0) red = S_LEN;
    __syncthreads();
    int m = S_LEN;
    for (int i = tid; i < S_LEN; i += 256)
        if (PAD[b * S_LEN + i] == 0) m = min(m, i);
    atomicMin(&red, m);
    __syncthreads();
    const int fz = red;                 // rows q < fz are fully masked
    if (fz == 0) return;

    const float* Vh = V + (size_t)bh * S_LEN * DH;
    float a = 0.f;
    const int dcol = tid & 63, part = tid >> 6;
    for (int kk = part; kk < S_LEN; kk += 4) a += Vh[(size_t)kk * DH + dcol];
    tmp[tid] = a;
    __syncthreads();
    if (tid < DH)
        vs[tid] = (tmp[tid] + tmp[tid + 64] + tmp[tid + 128] + tmp[tid + 192]) * (1.f / S_LEN);
    __syncthreads();

    float* Wh = W + (size_t)bh * S_LEN * S_LEN;
    float* Oh = OUT + (size_t)bh * S_LEN * DH;
    const f32x4 u = {1.f / S_LEN, 1.f / S_LEN, 1.f / S_LEN, 1.f / S_LEN};
    for (int qa2 = 0; qa2 < fz; ++qa2) {
        f32x4* dst = reinterpret_cast<f32x4*>(Wh + (size_t)qa2 * S_LEN);
        for (int i = tid; i < S_LEN / 4; i += 256) dst[i] = u;
        if (tid < DH) Oh[(size_t)qa2 * DH + tid] = vs[tid];
    }
}

extern "C" void kernel_launch(void* const* d_in, const int* in_sizes, int n_in,
                              void* d_out, int out_size, void* d_ws, size_t ws_size,
                              hipStream_t stream) {
    const float* q   = (const float*)d_in[0];
    const float* k   = (const float*)d_in[1];
    const float* v   = (const float*)d_in[2];
    // d_in[3] = causal mask: triu(k=1) structure, handled analytically
    const int*   pad = (const int*)d_in[4];

    float* out = (float*)d_out;                       // [4,16,2048,64]
    float* w   = out + (size_t)4 * 16 * S_LEN * DH;   // [4,16,2048,2048]

    attn_main<<<dim3(64 * 32), dim3(256), 0, stream>>>(q, k, v, pad, out, w);
    attn_fixup<<<dim3(64), dim3(256), 0, stream>>>(pad, v, out, w);
}

// Round 4
// 651.525 us; speedup vs baseline: 1.0066x; 1.0066x over previous
//
#include <hip/hip_runtime.h>
#include <hip/hip_bf16.h>

#define S_LEN 2048
#define DH    64
#define QT    64
#define KT    64
#define NW    4

typedef __attribute__((ext_vector_type(8))) short bf16x8;
typedef __attribute__((ext_vector_type(4))) float f32x4;
typedef __attribute__((ext_vector_type(4))) unsigned u32x4;
typedef __attribute__((ext_vector_type(2))) unsigned u32x2;

// native packed f32->bf16 (RNE), lo=a hi=b
static __device__ __forceinline__ unsigned cvtpk(float a, float b) {
    unsigned r;
    asm("v_cvt_pk_bf16_f32 %0, %1, %2" : "=v"(r) : "v"(a), "v"(b));
    return r;
}

__global__ __launch_bounds__(256) void attn_main(
    const float* __restrict__ Q, const float* __restrict__ K,
    const float* __restrict__ V, const int* __restrict__ PAD,
    float* __restrict__ OUT, float* __restrict__ W)
{
    __shared__ short Kt[KT][72];             // [key][d], rows 144B
    __shared__ short VT[DH][72];             // [d][key]
    __shared__ short Pb[NW][16][72];         // [q'][key], per-wave
    __shared__ float sinv[NW][16];           // 1/rowsum per q row
    __shared__ unsigned long long padm[32];  // pad bitmask

    // XCD-aware swizzle: each XCD owns 256 consecutive logical wgs = 8 heads
    const int orig = blockIdx.x;
    const int wg   = (orig & 7) * 256 + (orig >> 3);
    const int bh   = wg >> 5;
    const int qt   = 31 - (wg & 31);        // heavy tiles first
    const int b    = bh >> 4;
    const int q0   = qt * QT;

    const int tid  = threadIdx.x;
    const int wv   = tid >> 6;
    const int l    = tid & 63;
    const int lr   = l & 15;
    const int lg   = l >> 4;
    const int k2   = (tid & 31) * 2;        // V staging: key-pair base
    const int dblk = (tid >> 5) * 8;        // V staging: d block

    const size_t hoff = (size_t)bh * S_LEN * DH;
    const float* Qh = Q + hoff;
    const float* Kh = K + hoff;
    const float* Vh = V + hoff;
    float* Oh = OUT + hoff;
    float* Wh = W + (size_t)bh * S_LEN * S_LEN;

    const int nkt = qt + 1;

    // ---- prefetch tile kt=0 ----
    f32x4 pk0, pk1, pk2, pk3, pva0, pva1, pvb0, pvb1;
    {
        const float* kp = Kh + (size_t)l * DH + wv * 16;
        pk0 = *reinterpret_cast<const f32x4*>(kp);
        pk1 = *reinterpret_cast<const f32x4*>(kp + 4);
        pk2 = *reinterpret_cast<const f32x4*>(kp + 8);
        pk3 = *reinterpret_cast<const f32x4*>(kp + 12);
        const float* vp = Vh + (size_t)k2 * DH + dblk;
        pva0 = *reinterpret_cast<const f32x4*>(vp);
        pva1 = *reinterpret_cast<const f32x4*>(vp + 4);
        pvb0 = *reinterpret_cast<const f32x4*>(vp + DH);
        pvb1 = *reinterpret_cast<const f32x4*>(vp + DH + 4);
    }

    // pad bitmask via wave ballot
    for (int i = tid; i < S_LEN; i += 256) {
        unsigned long long m = __ballot(PAD[b * S_LEN + i] != 0);
        if (l == 0) padm[i >> 6] = m;
    }

    // ---- Q fragments (16 rows/wave), scale 1/8 folded in ----
    const int qrow = q0 + wv * 16 + lr;
    bf16x8 qf[2];
    {
        const float* qp = Qh + (size_t)qrow * DH + lg * 8;
        #pragma unroll
        for (int h = 0; h < 2; ++h) {
            f32x4 a  = *reinterpret_cast<const f32x4*>(qp + h * 32);
            f32x4 b4 = *reinterpret_cast<const f32x4*>(qp + h * 32 + 4);
            u32x4 t;
            t[0] = cvtpk(a[0] * 0.125f,  a[1] * 0.125f);
            t[1] = cvtpk(a[2] * 0.125f,  a[3] * 0.125f);
            t[2] = cvtpk(b4[0] * 0.125f, b4[1] * 0.125f);
            t[3] = cvtpk(b4[2] * 0.125f, b4[3] * 0.125f);
            qf[h] = __builtin_bit_cast(bf16x8, t);
        }
    }

    const f32x4 z4 = {0.f, 0.f, 0.f, 0.f};
    f32x4 acc[4] = {z4, z4, z4, z4};
    float rs = 0.f;                          // rowsum for q = q0+wv*16+lr (this lane's column)
    const int qcol = q0 + wv * 16 + lr;

    // =================== PASS A: swapped QK^T, rowsums + PV ===================
    for (int kt = 0; kt < nkt; ++kt) {
        __syncthreads();   // prev readers done
        {
            u32x4 ta, tb;
            ta[0] = cvtpk(pk0[0], pk0[1]); ta[1] = cvtpk(pk0[2], pk0[3]);
            ta[2] = cvtpk(pk1[0], pk1[1]); ta[3] = cvtpk(pk1[2], pk1[3]);
            tb[0] = cvtpk(pk2[0], pk2[1]); tb[1] = cvtpk(pk2[2], pk2[3]);
            tb[2] = cvtpk(pk3[0], pk3[1]); tb[3] = cvtpk(pk3[2], pk3[3]);
            *reinterpret_cast<u32x4*>(&Kt[l][wv * 16])     = ta;
            *reinterpret_cast<u32x4*>(&Kt[l][wv * 16 + 8]) = tb;
            #pragma unroll
            for (int j = 0; j < 4; ++j)
                *reinterpret_cast<unsigned*>(&VT[dblk + j][k2])     = cvtpk(pva0[j], pvb0[j]);
            #pragma unroll
            for (int j = 0; j < 4; ++j)
                *reinterpret_cast<unsigned*>(&VT[dblk + 4 + j][k2]) = cvtpk(pva1[j], pvb1[j]);
        }
        __syncthreads();   // tile kt visible

        // issue next tile's loads now (fly across the compute phase)
        if (kt + 1 < nkt) {
            const float* kp = Kh + ((size_t)((kt + 1) * KT) + l) * DH + wv * 16;
            pk0 = *reinterpret_cast<const f32x4*>(kp);
            pk1 = *reinterpret_cast<const f32x4*>(kp + 4);
            pk2 = *reinterpret_cast<const f32x4*>(kp + 8);
            pk3 = *reinterpret_cast<const f32x4*>(kp + 12);
            const float* vp = Vh + ((size_t)((kt + 1) * KT) + k2) * DH + dblk;
            pva0 = *reinterpret_cast<const f32x4*>(vp);
            pva1 = *reinterpret_cast<const f32x4*>(vp + 4);
            pvb0 = *reinterpret_cast<const f32x4*>(vp + DH);
            pvb1 = *reinterpret_cast<const f32x4*>(vp + DH + 4);
        }

        const unsigned long long pm = padm[kt];

        // swapped QK^T: sc[s] = K_sub * Q^T -> lane holds q-col lr, keys s*16+lg*4+(0..3)
        f32x4 sc[4] = {z4, z4, z4, z4};
        #pragma unroll
        for (int s = 0; s < 4; ++s)
            #pragma unroll
            for (int h = 0; h < 2; ++h) {
                bf16x8 kf = *reinterpret_cast<const bf16x8*>(&Kt[s * 16 + lr][h * 32 + lg * 8]);
                sc[s] = __builtin_amdgcn_mfma_f32_16x16x32_bf16(kf, qf[h], sc[s], 0, 0, 0);
            }

        // exp + masks + rowsum + packed P -> LDS
        #pragma unroll
        for (int s = 0; s < 4; ++s) {
            const int kbase = kt * KT + s * 16 + lg * 4;
            float e[4];
            #pragma unroll
            for (int r = 0; r < 4; ++r) {
                const bool padded = (pm >> (s * 16 + lg * 4 + r)) & 1ull;
                const bool ok = (kbase + r <= qcol) && !padded;
                e[r] = ok ? __expf(sc[s][r]) : 0.f;
                rs += e[r];
            }
            u32x2 p2 = { cvtpk(e[0], e[1]), cvtpk(e[2], e[3]) };
            *reinterpret_cast<u32x2*>(&Pb[wv][lr][s * 16 + lg * 4]) = p2;
        }
        // no barrier: Pb is per-wave

        // PV: acc[16q x 64d] += P(16x64) * V(64x64)
        #pragma unroll
        for (int kk = 0; kk < 2; ++kk) {
            bf16x8 pf = *reinterpret_cast<const bf16x8*>(&Pb[wv][lr][kk * 32 + lg * 8]);
            #pragma unroll
            for (int dt = 0; dt < 4; ++dt) {
                bf16x8 vf = *reinterpret_cast<const bf16x8*>(&VT[dt * 16 + lr][kk * 32 + lg * 8]);
                acc[dt] = __builtin_amdgcn_mfma_f32_16x16x32_bf16(pf, vf, acc[dt], 0, 0, 0);
            }
        }
    }

    // rowsum: lanes with same lr across lg hold disjoint key subsets -> 2 shuffles
    rs += __shfl_xor(rs, 16, 64);
    rs += __shfl_xor(rs, 32, 64);
    const float inv = rs > 0.f ? 1.f / rs : 0.f;   // 0 => fixup kernel

    // redistribute inv to O-store layout (same-wave LDS, no barrier)
    if (lg == 0) sinv[wv][lr] = inv;
    float inv4[4];
    #pragma unroll
    for (int r = 0; r < 4; ++r) inv4[r] = sinv[wv][lg * 4 + r];

    // store attention output (acc rows: q = q0+wv*16+lg*4+r, cols d = dt*16+lr)
    const int qa = q0 + wv * 16 + lg * 4;
    #pragma unroll
    for (int dt = 0; dt < 4; ++dt)
        #pragma unroll
        for (int r = 0; r < 4; ++r)
            Oh[(size_t)(qa + r) * DH + dt * 16 + lr] = acc[dt][r] * inv4[r];

    // =================== PASS B: swapped QK^T, direct W stores ===================
    {
        const float* kp = Kh + (size_t)l * DH + wv * 16;
        pk0 = *reinterpret_cast<const f32x4*>(kp);
        pk1 = *reinterpret_cast<const f32x4*>(kp + 4);
        pk2 = *reinterpret_cast<const f32x4*>(kp + 8);
        pk3 = *reinterpret_cast<const f32x4*>(kp + 12);
    }

    for (int kt = 0; kt < nkt; ++kt) {
        __syncthreads();
        {
            u32x4 ta, tb;
            ta[0] = cvtpk(pk0[0], pk0[1]); ta[1] = cvtpk(pk0[2], pk0[3]);
            ta[2] = cvtpk(pk1[0], pk1[1]); ta[3] = cvtpk(pk1[2], pk1[3]);
            tb[0] = cvtpk(pk2[0], pk2[1]); tb[1] = cvtpk(pk2[2], pk2[3]);
            tb[2] = cvtpk(pk3[0], pk3[1]); tb[3] = cvtpk(pk3[2], pk3[3]);
            *reinterpret_cast<u32x4*>(&Kt[l][wv * 16])     = ta;
            *reinterpret_cast<u32x4*>(&Kt[l][wv * 16 + 8]) = tb;
        }
        __syncthreads();

        if (kt + 1 < nkt) {
            const float* kp = Kh + ((size_t)((kt + 1) * KT) + l) * DH + wv * 16;
            pk0 = *reinterpret_cast<const f32x4*>(kp);
            pk1 = *reinterpret_cast<const f32x4*>(kp + 4);
            pk2 = *reinterpret_cast<const f32x4*>(kp + 8);
            pk3 = *reinterpret_cast<const f32x4*>(kp + 12);
        }

        const unsigned long long pm = padm[kt];

        f32x4 sc[4] = {z4, z4, z4, z4};
        #pragma unroll
        for (int s = 0; s < 4; ++s)
            #pragma unroll
            for (int h = 0; h < 2; ++h) {
                bf16x8 kf = *reinterpret_cast<const bf16x8*>(&Kt[s * 16 + lr][h * 32 + lg * 8]);
                sc[s] = __builtin_amdgcn_mfma_f32_16x16x32_bf16(kf, qf[h], sc[s], 0, 0, 0);
            }

        // lane holds keys kt*64 + s*16 + lg*4 + (0..3) for q row qcol; inv already lane-correct
        #pragma unroll
        for (int s = 0; s < 4; ++s) {
            const int kbase = kt * KT + s * 16 + lg * 4;
            f32x4 t;
            #pragma unroll
            for (int r = 0; r < 4; ++r) {
                const bool padded = (pm >> (s * 16 + lg * 4 + r)) & 1ull;
                const bool ok = (kbase + r <= qcol) && !padded;
                t[r] = ok ? __expf(sc[s][r]) * inv : 0.f;
            }
            *reinterpret_cast<f32x4*>(Wh + (size_t)qcol * S_LEN + kbase) = t;
        }
    }

    // zero-fill the beyond-causal rectangle k in [kend, S)
    {
        const int kend = q0 + QT;
        const int ntail4 = (S_LEN - kend) >> 2;
        for (int row = 0; row < QT; ++row) {
            f32x4* dst = reinterpret_cast<f32x4*>(Wh + (size_t)(q0 + row) * S_LEN + kend);
            for (int i = tid; i < ntail4; i += 256) dst[i] = z4;
        }
    }
}

// rows fully masked (all k<=q padded): reference softmax = uniform 1/S over ALL keys
__global__ __launch_bounds__(256) void attn_fixup(
    const int* __restrict__ PAD, const float* __restrict__ V,
    float* __restrict__ OUT, float* __restrict__ W)
{
    const int bh = blockIdx.x;
    const int b  = bh >> 4;
    const int tid = threadIdx.x;
    __shared__ int red;
    __shared__ float tmp[256];
    __shared__ float vs[DH];
    if (tid == 0) red = S_LEN;
    __syncthreads();
    int m = S_LEN;
    for (int i = tid; i < S_LEN; i += 256)
        if (PAD[b * S_LEN + i] == 0) m = min(m, i);
    atomicMin(&red, m);
    __syncthreads();
    const int fz = red;                 // rows q < fz are fully masked
    if (fz == 0) return;                // early-exit BEFORE the V reduction

    const float* Vh = V + (size_t)bh * S_LEN * DH;
    float a = 0.f;
    const int dcol = tid & 63, part = tid >> 6;
    for (int kk = part; kk < S_LEN; kk += 4) a += Vh[(size_t)kk * DH + dcol];
    tmp[tid] = a;
    __syncthreads();
    if (tid < DH)
        vs[tid] = (tmp[tid] + tmp[tid + 64] + tmp[tid + 128] + tmp[tid + 192]) * (1.f / S_LEN);
    __syncthreads();

    float* Wh = W + (size_t)bh * S_LEN * S_LEN;
    float* Oh = OUT + (size_t)bh * S_LEN * DH;
    const f32x4 u = {1.f / S_LEN, 1.f / S_LEN, 1.f / S_LEN, 1.f / S_LEN};
    for (int qa2 = 0; qa2 < fz; ++qa2) {
        f32x4* dst = reinterpret_cast<f32x4*>(Wh + (size_t)qa2 * S_LEN);
        for (int i = tid; i < S_LEN / 4; i += 256) dst[i] = u;
        if (tid < DH) Oh[(size_t)qa2 * DH + tid] = vs[tid];
    }
}

extern "C" void kernel_launch(void* const* d_in, const int* in_sizes, int n_in,
                              void* d_out, int out_size, void* d_ws, size_t ws_size,
                              hipStream_t stream) {
    const float* q   = (const float*)d_in[0];
    const float* k   = (const float*)d_in[1];
    const float* v   = (const float*)d_in[2];
    // d_in[3] = causal mask: triu(k=1) structure, handled analytically
    const int*   pad = (const int*)d_in[4];

    float* out = (float*)d_out;                       // [4,16,2048,64]
    float* w   = out + (size_t)4 * 16 * S_LEN * DH;   // [4,16,2048,2048]

    attn_main<<<dim3(64 * 32), dim3(256), 0, stream>>>(q, k, v, pad, out, w);
    attn_fixup<<<dim3(64), dim3(256), 0, stream>>>(pad, v, out, w);
}

// Round 5
// 472.701 us; speedup vs baseline: 1.3874x; 1.3783x over previous
//
#include <hip/hip_runtime.h>
#include <hip/hip_bf16.h>

#define S_LEN 2048
#define DH    64
#define QT    128
#define KT    64
#define NW    4

typedef __attribute__((ext_vector_type(8))) short bf16x8;
typedef __attribute__((ext_vector_type(4))) float f32x4;
typedef __attribute__((ext_vector_type(4))) unsigned u32x4;
typedef __attribute__((ext_vector_type(2))) unsigned u32x2;

// native packed f32->bf16 (RNE), lo=a hi=b
static __device__ __forceinline__ unsigned cvtpk(float a, float b) {
    unsigned r;
    asm("v_cvt_pk_bf16_f32 %0, %1, %2" : "=v"(r) : "v"(a), "v"(b));
    return r;
}

__global__ __launch_bounds__(256) void attn_main(
    const float* __restrict__ Q, const float* __restrict__ K,
    const float* __restrict__ V, const int* __restrict__ PAD,
    float* __restrict__ OUT, float* __restrict__ W)
{
    __shared__ short Kt[KT][72];             // [key][d], rows 144B
    __shared__ short VT[DH][72];             // [d][key]
    __shared__ short Pb[NW][16][72];         // [q'][key], per-wave scratch
    __shared__ float sinv[2][NW][16];        // 1/rowsum, per q-block
    __shared__ unsigned long long padm[32];  // pad bitmask

    // XCD-aware swizzle: each XCD owns 128 consecutive logical wgs = 8 heads
    const int orig = blockIdx.x;
    const int wg   = (orig & 7) * 128 + (orig >> 3);
    const int bh   = wg >> 4;
    const int qt   = 15 - (wg & 15);        // heavy tiles first
    const int b    = bh >> 4;
    const int q0   = qt * QT;

    const int tid  = threadIdx.x;
    const int wv   = tid >> 6;
    const int l    = tid & 63;
    const int lr   = l & 15;
    const int lg   = l >> 4;
    const int k2   = (tid & 31) * 2;        // V staging: key-pair base
    const int dblk = (tid >> 5) * 8;        // V staging: d block

    const size_t hoff = (size_t)bh * S_LEN * DH;
    const float* Qh = Q + hoff;
    const float* Kh = K + hoff;
    const float* Vh = V + hoff;
    float* Oh = OUT + hoff;
    float* Wh = W + (size_t)bh * S_LEN * S_LEN;

    const int nkt    = 2 * qt + 2;          // k-tiles covering [0, q0+128)
    const int ktmaxA = 2 * qt;              // block A (rows q0..q0+63) active for kt<=ktmaxA

    // pad bitmask via wave ballot
    for (int i = tid; i < S_LEN; i += 256) {
        unsigned long long m = __ballot(PAD[b * S_LEN + i] != 0);
        if (l == 0) padm[i >> 6] = m;
    }

    // ---- Q fragments for both q-blocks (16 rows/wave each), scale 1/8 folded ----
    bf16x8 qfA[2], qfB[2];
    #pragma unroll
    for (int blk = 0; blk < 2; ++blk) {
        const float* qp = Qh + (size_t)(q0 + blk * 64 + wv * 16 + lr) * DH + lg * 8;
        #pragma unroll
        for (int h = 0; h < 2; ++h) {
            f32x4 a  = *reinterpret_cast<const f32x4*>(qp + h * 32);
            f32x4 b4 = *reinterpret_cast<const f32x4*>(qp + h * 32 + 4);
            u32x4 t;
            t[0] = cvtpk(a[0] * 0.125f,  a[1] * 0.125f);
            t[1] = cvtpk(a[2] * 0.125f,  a[3] * 0.125f);
            t[2] = cvtpk(b4[0] * 0.125f, b4[1] * 0.125f);
            t[3] = cvtpk(b4[2] * 0.125f, b4[3] * 0.125f);
            (blk ? qfB[h] : qfA[h]) = __builtin_bit_cast(bf16x8, t);
        }
    }

    const f32x4 z4 = {0.f, 0.f, 0.f, 0.f};
    f32x4 accA[4] = {z4, z4, z4, z4};
    f32x4 accB[4] = {z4, z4, z4, z4};
    float rsA = 0.f, rsB = 0.f;
    const int qcolA = q0 + wv * 16 + lr;
    const int qcolB = qcolA + 64;

    // one q-block's QK^T + exp + PV for the staged tile
    auto ablock = [&](const bf16x8 (&qf)[2], const int qcol, float& rsref,
                      f32x4 (&accb)[4], const unsigned long long pm, const int ktbase) {
        f32x4 sc[4] = {z4, z4, z4, z4};
        #pragma unroll
        for (int s = 0; s < 4; ++s)
            #pragma unroll
            for (int h = 0; h < 2; ++h) {
                bf16x8 kf = *reinterpret_cast<const bf16x8*>(&Kt[s * 16 + lr][h * 32 + lg * 8]);
                sc[s] = __builtin_amdgcn_mfma_f32_16x16x32_bf16(kf, qf[h], sc[s], 0, 0, 0);
            }
        #pragma unroll
        for (int s = 0; s < 4; ++s) {
            const int kbase = ktbase + s * 16 + lg * 4;
            float e[4];
            #pragma unroll
            for (int r = 0; r < 4; ++r) {
                const bool padded = (pm >> (s * 16 + lg * 4 + r)) & 1ull;
                const bool ok = (kbase + r <= qcol) && !padded;
                e[r] = ok ? __expf(sc[s][r]) : 0.f;
                rsref += e[r];
            }
            u32x2 p2 = { cvtpk(e[0], e[1]), cvtpk(e[2], e[3]) };
            *reinterpret_cast<u32x2*>(&Pb[wv][lr][s * 16 + lg * 4]) = p2;
        }
        #pragma unroll
        for (int kk = 0; kk < 2; ++kk) {
            bf16x8 pf = *reinterpret_cast<const bf16x8*>(&Pb[wv][lr][kk * 32 + lg * 8]);
            #pragma unroll
            for (int dt = 0; dt < 4; ++dt) {
                bf16x8 vf = *reinterpret_cast<const bf16x8*>(&VT[dt * 16 + lr][kk * 32 + lg * 8]);
                accb[dt] = __builtin_amdgcn_mfma_f32_16x16x32_bf16(pf, vf, accb[dt], 0, 0, 0);
            }
        }
    };

    // =================== PASS A: rowsums + PV (K/V staged once per 128 q-rows) ===================
    for (int kt = 0; kt < nkt; ++kt) {
        __syncthreads();
        {   // stage K + V (fp32 -> bf16 via cvt_pk)
            const float* kp = Kh + ((size_t)(kt * KT) + l) * DH + wv * 16;
            f32x4 pk0 = *reinterpret_cast<const f32x4*>(kp);
            f32x4 pk1 = *reinterpret_cast<const f32x4*>(kp + 4);
            f32x4 pk2 = *reinterpret_cast<const f32x4*>(kp + 8);
            f32x4 pk3 = *reinterpret_cast<const f32x4*>(kp + 12);
            const float* vp = Vh + ((size_t)(kt * KT) + k2) * DH + dblk;
            f32x4 pva0 = *reinterpret_cast<const f32x4*>(vp);
            f32x4 pva1 = *reinterpret_cast<const f32x4*>(vp + 4);
            f32x4 pvb0 = *reinterpret_cast<const f32x4*>(vp + DH);
            f32x4 pvb1 = *reinterpret_cast<const f32x4*>(vp + DH + 4);
            u32x4 ta, tb;
            ta[0] = cvtpk(pk0[0], pk0[1]); ta[1] = cvtpk(pk0[2], pk0[3]);
            ta[2] = cvtpk(pk1[0], pk1[1]); ta[3] = cvtpk(pk1[2], pk1[3]);
            tb[0] = cvtpk(pk2[0], pk2[1]); tb[1] = cvtpk(pk2[2], pk2[3]);
            tb[2] = cvtpk(pk3[0], pk3[1]); tb[3] = cvtpk(pk3[2], pk3[3]);
            *reinterpret_cast<u32x4*>(&Kt[l][wv * 16])     = ta;
            *reinterpret_cast<u32x4*>(&Kt[l][wv * 16 + 8]) = tb;
            #pragma unroll
            for (int j = 0; j < 4; ++j)
                *reinterpret_cast<unsigned*>(&VT[dblk + j][k2])     = cvtpk(pva0[j], pvb0[j]);
            #pragma unroll
            for (int j = 0; j < 4; ++j)
                *reinterpret_cast<unsigned*>(&VT[dblk + 4 + j][k2]) = cvtpk(pva1[j], pvb1[j]);
        }
        __syncthreads();

        const unsigned long long pm = padm[kt];
        if (kt <= ktmaxA) ablock(qfA, qcolA, rsA, accA, pm, kt * KT);
        ablock(qfB, qcolB, rsB, accB, pm, kt * KT);
    }

    // rowsum reduce (lanes sharing lr across lg hold disjoint key subsets)
    rsA += __shfl_xor(rsA, 16, 64); rsA += __shfl_xor(rsA, 32, 64);
    rsB += __shfl_xor(rsB, 16, 64); rsB += __shfl_xor(rsB, 32, 64);
    const float invA = rsA > 0.f ? 1.f / rsA : 0.f;
    const float invB = rsB > 0.f ? 1.f / rsB : 0.f;

    // redistribute inv to O-store layout (same-wave LDS, no barrier)
    if (lg == 0) { sinv[0][wv][lr] = invA; sinv[1][wv][lr] = invB; }
    float inv4A[4], inv4B[4];
    #pragma unroll
    for (int r = 0; r < 4; ++r) {
        inv4A[r] = sinv[0][wv][lg * 4 + r];
        inv4B[r] = sinv[1][wv][lg * 4 + r];
    }

    // store O for both blocks (rows q0 + blk*64 + wv*16 + lg*4 + r, col dt*16+lr)
    const int qa = q0 + wv * 16 + lg * 4;
    #pragma unroll
    for (int dt = 0; dt < 4; ++dt)
        #pragma unroll
        for (int r = 0; r < 4; ++r) {
            Oh[(size_t)(qa + r) * DH + dt * 16 + lr]      = accA[dt][r] * inv4A[r];
            Oh[(size_t)(qa + 64 + r) * DH + dt * 16 + lr] = accB[dt][r] * inv4B[r];
        }

    // =================== PASS B: recompute, nontemporal W stores ===================
    auto wblock = [&](const bf16x8 (&qf)[2], const int qcol, const float inv,
                      const unsigned long long pm, const int ktbase) {
        f32x4 sc[4] = {z4, z4, z4, z4};
        #pragma unroll
        for (int s = 0; s < 4; ++s)
            #pragma unroll
            for (int h = 0; h < 2; ++h) {
                bf16x8 kf = *reinterpret_cast<const bf16x8*>(&Kt[s * 16 + lr][h * 32 + lg * 8]);
                sc[s] = __builtin_amdgcn_mfma_f32_16x16x32_bf16(kf, qf[h], sc[s], 0, 0, 0);
            }
        #pragma unroll
        for (int s = 0; s < 4; ++s) {
            const int kbase = ktbase + s * 16 + lg * 4;
            f32x4 t;
            #pragma unroll
            for (int r = 0; r < 4; ++r) {
                const bool padded = (pm >> (s * 16 + lg * 4 + r)) & 1ull;
                const bool ok = (kbase + r <= qcol) && !padded;
                t[r] = ok ? __expf(sc[s][r]) * inv : 0.f;
            }
            __builtin_nontemporal_store(t,
                reinterpret_cast<f32x4*>(Wh + (size_t)qcol * S_LEN + kbase));
        }
    };

    for (int kt = 0; kt < nkt; ++kt) {
        __syncthreads();
        {   // stage K only
            const float* kp = Kh + ((size_t)(kt * KT) + l) * DH + wv * 16;
            f32x4 pk0 = *reinterpret_cast<const f32x4*>(kp);
            f32x4 pk1 = *reinterpret_cast<const f32x4*>(kp + 4);
            f32x4 pk2 = *reinterpret_cast<const f32x4*>(kp + 8);
            f32x4 pk3 = *reinterpret_cast<const f32x4*>(kp + 12);
            u32x4 ta, tb;
            ta[0] = cvtpk(pk0[0], pk0[1]); ta[1] = cvtpk(pk0[2], pk0[3]);
            ta[2] = cvtpk(pk1[0], pk1[1]); ta[3] = cvtpk(pk1[2], pk1[3]);
            tb[0] = cvtpk(pk2[0], pk2[1]); tb[1] = cvtpk(pk2[2], pk2[3]);
            tb[2] = cvtpk(pk3[0], pk3[1]); tb[3] = cvtpk(pk3[2], pk3[3]);
            *reinterpret_cast<u32x4*>(&Kt[l][wv * 16])     = ta;
            *reinterpret_cast<u32x4*>(&Kt[l][wv * 16 + 8]) = tb;
        }
        __syncthreads();

        const unsigned long long pm = padm[kt];
        if (kt <= ktmaxA) wblock(qfA, qcolA, invA, pm, kt * KT);
        wblock(qfB, qcolB, invB, pm, kt * KT);
    }

    // zero-fill beyond-causal rectangles (nontemporal)
    {
        #pragma unroll 1
        for (int row = 0; row < QT; ++row) {
            const int kend = q0 + (row < 64 ? 64 : 128);
            const int n4 = (S_LEN - kend) >> 2;
            f32x4* dst = reinterpret_cast<f32x4*>(Wh + (size_t)(q0 + row) * S_LEN + kend);
            for (int i = tid; i < n4; i += 256)
                __builtin_nontemporal_store(z4, dst + i);
        }
    }
}

// rows fully masked (all k<=q padded): reference softmax = uniform 1/S over ALL keys
__global__ __launch_bounds__(256) void attn_fixup(
    const int* __restrict__ PAD, const float* __restrict__ V,
    float* __restrict__ OUT, float* __restrict__ W)
{
    const int bh = blockIdx.x;
    const int b  = bh >> 4;
    const int tid = threadIdx.x;
    __shared__ int red;
    __shared__ float tmp[256];
    __shared__ float vs[DH];
    if (tid == 0) red = S_LEN;
    __syncthreads();
    int m = S_LEN;
    for (int i = tid; i < S_LEN; i += 256)
        if (PAD[b * S_LEN + i] == 0) m = min(m, i);
    atomicMin(&red, m);
    __syncthreads();
    const int fz = red;                 // rows q < fz are fully masked
    if (fz == 0) return;                // early-exit BEFORE the V reduction

    const float* Vh = V + (size_t)bh * S_LEN * DH;
    float a = 0.f;
    const int dcol = tid & 63, part = tid >> 6;
    for (int kk = part; kk < S_LEN; kk += 4) a += Vh[(size_t)kk * DH + dcol];
    tmp[tid] = a;
    __syncthreads();
    if (tid < DH)
        vs[tid] = (tmp[tid] + tmp[tid + 64] + tmp[tid + 128] + tmp[tid + 192]) * (1.f / S_LEN);
    __syncthreads();

    float* Wh = W + (size_t)bh * S_LEN * S_LEN;
    float* Oh = OUT + (size_t)bh * S_LEN * DH;
    const f32x4 u = {1.f / S_LEN, 1.f / S_LEN, 1.f / S_LEN, 1.f / S_LEN};
    for (int qa2 = 0; qa2 < fz; ++qa2) {
        f32x4* dst = reinterpret_cast<f32x4*>(Wh + (size_t)qa2 * S_LEN);
        for (int i = tid; i < S_LEN / 4; i += 256) dst[i] = u;
        if (tid < DH) Oh[(size_t)qa2 * DH + tid] = vs[tid];
    }
}

extern "C" void kernel_launch(void* const* d_in, const int* in_sizes, int n_in,
                              void* d_out, int out_size, void* d_ws, size_t ws_size,
                              hipStream_t stream) {
    const float* q   = (const float*)d_in[0];
    const float* k   = (const float*)d_in[1];
    const float* v   = (const float*)d_in[2];
    // d_in[3] = causal mask: triu(k=1) structure, handled analytically
    const int*   pad = (const int*)d_in[4];

    float* out = (float*)d_out;                       // [4,16,2048,64]
    float* w   = out + (size_t)4 * 16 * S_LEN * DH;   // [4,16,2048,2048]

    attn_main<<<dim3(64 * 16), dim3(256), 0, stream>>>(q, k, v, pad, out, w);
    attn_fixup<<<dim3(64), dim3(256), 0, stream>>>(pad, v, out, w);
}